// Round 1
// baseline (4183.913 us; speedup 1.0000x reference)
//
#include <hip/hip_runtime.h>
#include <stdint.h>

#define B_   512
#define H_   1024
#define S_   128
#define OUT_ 49

typedef __attribute__((ext_vector_type(8))) short short8;
typedef __attribute__((ext_vector_type(4))) float f32x4;

__device__ __forceinline__ unsigned short f2bf(float f) {
  union { float f; uint32_t u; } v; v.f = f;
  return (unsigned short)((v.u + 0x7FFFu + ((v.u >> 16) & 1u)) >> 16);  // RNE
}
__device__ __forceinline__ float sigmoidf_(float x) { return 1.0f / (1.0f + __expf(-x)); }
__device__ __forceinline__ float tanhf_(float x)    { return 2.0f / (1.0f + __expf(-2.0f * x)) - 1.0f; }

__device__ __forceinline__ void gload16(const void* gp, void* lp) {
  // async global->LDS, 16B per lane; LDS dest is wave-uniform base + lane*16
  __builtin_amdgcn_global_load_lds(
      (const __attribute__((address_space(1))) void*)gp,
      (__attribute__((address_space(3))) void*)lp, 16, 0, 0);
}

// ---------------------------------------------------------------------------
// Pack fp32 weights [rows x src_cols] into MFMA-fragment-linear bf16:
// frag id = s*RT + rt ; lane l holds (row = rt*16 + (l&15), k = s*32 + (l>>4)*8 .. +8)
// For s >= s_split the source switches to srcB with s' = s - s_split (K-concat).
// Rows >= src_rows are zero-padded (used for W_out's 49->64 pad).
// ---------------------------------------------------------------------------
__global__ void pack_frags_kernel(const float* __restrict__ srcA,
                                  const float* __restrict__ srcB,
                                  unsigned short* __restrict__ dst,
                                  int RT, int S_total, int s_split,
                                  int src_rows, int src_cols) {
  int gid = blockIdx.x * blockDim.x + threadIdx.x;
  int total = S_total * RT * 64;
  if (gid >= total) return;
  int l  = gid & 63;
  int rt = (gid >> 6) % RT;
  int s  = gid / (RT * 64);
  int row = rt * 16 + (l & 15);
  const float* src = srcA;
  int scol = s;
  if (s >= s_split) { src = srcB; scol = s - s_split; }
  int col = scol * 32 + (l >> 4) * 8;
  short8 v;
  if (row < src_rows) {
    const float* p = src + (size_t)row * src_cols + col;
#pragma unroll
    for (int e = 0; e < 8; ++e) v[e] = (short)f2bf(p[e]);
  } else {
#pragma unroll
    for (int e = 0; e < 8; ++e) v[e] = 0;
  }
  *reinterpret_cast<short8*>(dst + (size_t)gid * 8) = v;
}

__global__ void prep_bias_kernel(const float* __restrict__ bi0, const float* __restrict__ bh0,
                                 const float* __restrict__ bi1, const float* __restrict__ bh1,
                                 float* __restrict__ b0, float* __restrict__ b1) {
  int i = blockIdx.x * blockDim.x + threadIdx.x;
  if (i < 4096) { b0[i] = bi0[i] + bh0[i]; b1[i] = bi1[i] + bh1[i]; }
}

// hidden/cell init: [512,2048] = z @ W^T + b, split into layer 0/1 h0 (bf16, ring slot 1) and c0 (fp32)
__global__ void init_hc_kernel(const float* __restrict__ z,
                               const float* __restrict__ W_hid, const float* __restrict__ b_hid,
                               const float* __restrict__ W_cell, const float* __restrict__ b_cell,
                               unsigned short* __restrict__ h1_ring, unsigned short* __restrict__ h2_ring,
                               float* __restrict__ c_l0, float* __restrict__ c_l1) {
  __shared__ float zs[64];
  int b = blockIdx.x;
  if (threadIdx.x < 64) zs[threadIdx.x] = z[b * 64 + threadIdx.x];
  __syncthreads();
  for (int j = threadIdx.x; j < 2048; j += blockDim.x) {
    float ah = b_hid[j], ac = b_cell[j];
    const float* wh = W_hid + (size_t)j * 64;
    const float* wc = W_cell + (size_t)j * 64;
#pragma unroll 8
    for (int k = 0; k < 64; ++k) { ah += zs[k] * wh[k]; ac += zs[k] * wc[k]; }
    int layer = j >> 10, n = j & 1023;
    if (layer == 0) {
      h1_ring[(size_t)B_ * H_ + (size_t)b * H_ + n] = f2bf(ah);  // slot 1 == step "-1"
      c_l0[(size_t)b * H_ + n] = ac;
    } else {
      h2_ring[(size_t)B_ * H_ + (size_t)b * H_ + n] = f2bf(ah);
      c_l1[(size_t)b * H_ + n] = ac;
    }
  }
}

// ---------------------------------------------------------------------------
// Super-step kernel, launch k = 0..129:
//   blocks [0,256)   : layer-0 LSTM step t = k        (t in [0,128))
//   blocks [256,512) : layer-1 LSTM step t = k-1
//   blocks [512,520) : output projection step t = k-2
// All producer->consumer deps are cross-launch (ring-2 buffers).
// LSTM tile: BM=64 x BN=32 x 4 gates, K = 1024 (L0) / 2048 (L1 concat [x|h]).
// ---------------------------------------------------------------------------
__global__ __launch_bounds__(256)
void step_kernel(int k,
                 const unsigned short* __restrict__ W0p, const unsigned short* __restrict__ W1p,
                 const unsigned short* __restrict__ Woutp,
                 const float* __restrict__ b0, const float* __restrict__ b1,
                 const float* __restrict__ b_out,
                 float* __restrict__ c_l0, float* __restrict__ c_l1,
                 unsigned short* __restrict__ h1_ring, unsigned short* __restrict__ h2_ring,
                 float* __restrict__ out) {
  __shared__ __attribute__((aligned(128))) unsigned char smem[24 * 1024];
  unsigned char* ldsA = smem;           // 8 KiB : 64 rows x 128 B (XOR-chunk-swizzled)
  unsigned char* ldsB = smem + 8192;    // 16 KiB: 16 frag slots x 1 KiB (frag-linear)
  const int wg  = blockIdx.x;
  const int tid = threadIdx.x;
  const int w = tid >> 6, l = tid & 63;

  if (wg < 512) {
    const int role = wg >> 8;                 // 0 = layer0, 1 = layer1
    const int t = (role == 0) ? k : k - 1;
    if (t < 0 || t > 127) return;
    const int id = wg & 255;
    const int bt = id >> 5, nt2 = id & 31;    // batch tile (64 rows), n-range (32 cols)
    const unsigned short* Wp  = role ? W1p : W0p;
    const float* bias         = role ? b1 : b0;
    float* cptr               = role ? c_l1 : c_l0;
    unsigned short* ring      = role ? h2_ring : h1_ring;
    const int KC              = role ? 32 : 16;  // K/64 chunks
    const unsigned short* hprev = ring + (size_t)((t + 1) & 1) * (B_ * H_);
    const unsigned short* xsrc  = h1_ring + (size_t)(t & 1) * (B_ * H_);   // layer-1 x = h1[t]
    unsigned short* hout        = ring + (size_t)(t & 1) * (B_ * H_);

    const int wm = w >> 1, wn = w & 1;        // 2x2 wave grid: 32 rows x 16 cols each
    f32x4 acc[2][4];
#pragma unroll
    for (int mt = 0; mt < 2; ++mt)
#pragma unroll
      for (int g = 0; g < 4; ++g) acc[mt][g] = (f32x4)0.0f;

    for (int kc = 0; kc < KC; ++kc) {
      // ---- stage A (h / [x|h]) : 64 rows x 128 B, XOR-swizzled chunks ----
#pragma unroll
      for (int q2 = 0; q2 < 2; ++q2) {
        int q = w * 2 + q2;                  // 8 rows per issue
        int rr = q * 8 + (l >> 3);
        int c  = l & 7;
        const unsigned short* srow;
        int kbyte;
        if (role == 0 || kc < 16) {          // L0: always hprev; L1: first 1024 K = x
          srow = (role ? xsrc : hprev) + (size_t)(bt * 64 + rr) * H_;
          kbyte = kc * 128;
        } else {                              // L1: second 1024 K = hprev
          srow = hprev + (size_t)(bt * 64 + rr) * H_;
          kbyte = (kc - 16) * 128;
        }
        gload16((const unsigned char*)srow + kbyte + ((c ^ (rr & 7)) * 16),
                ldsA + q * 1024);
      }
      // ---- stage B (weights, frag-linear): 16 frags of 1 KiB ----
#pragma unroll
      for (int r2 = 0; r2 < 4; ++r2) {
        int r  = w * 4 + r2;                  // r = s2*8 + g*2 + jj
        int s2 = r >> 3, gg = (r >> 1) & 3, jj = r & 1;
        size_t frag = ((size_t)(kc * 2 + s2) * 256) + (size_t)gg * 64 + (nt2 * 2 + jj);
        gload16((const unsigned char*)Wp + frag * 1024 + (size_t)l * 16,
                ldsB + r * 1024);
      }
      __syncthreads();                        // drains vmcnt -> LDS ready
      // ---- 16 MFMAs per chunk per wave ----
#pragma unroll
      for (int s2 = 0; s2 < 2; ++s2) {
        short8 a[2], bb[4];
#pragma unroll
        for (int mt = 0; mt < 2; ++mt) {
          int rl = wm * 32 + mt * 16 + (l & 15);
          int c  = s2 * 4 + (l >> 4);
          a[mt] = *reinterpret_cast<const short8*>(ldsA + rl * 128 + ((c ^ (rl & 7)) * 16));
        }
#pragma unroll
        for (int g = 0; g < 4; ++g)
          bb[g] = *reinterpret_cast<const short8*>(ldsB + (s2 * 8 + g * 2 + wn) * 1024 + l * 16);
#pragma unroll
        for (int mt = 0; mt < 2; ++mt)
#pragma unroll
          for (int g = 0; g < 4; ++g)
            acc[mt][g] = __builtin_amdgcn_mfma_f32_16x16x32_bf16(a[mt], bb[g], acc[mt][g], 0, 0, 0);
      }
      __syncthreads();                        // protect LDS reuse next chunk
    }
    // ---- epilogue: fused LSTM cell update ----
    const int n = nt2 * 32 + wn * 16 + (l & 15);
#pragma unroll
    for (int mt = 0; mt < 2; ++mt) {
#pragma unroll
      for (int r = 0; r < 4; ++r) {
        int m = bt * 64 + wm * 32 + mt * 16 + (l >> 4) * 4 + r;
        float pi = acc[mt][0][r] + bias[n];
        float pf = acc[mt][1][r] + bias[1024 + n];
        float pg = acc[mt][2][r] + bias[2048 + n];
        float po = acc[mt][3][r] + bias[3072 + n];
        size_t idx = (size_t)m * H_ + n;
        float co = cptr[idx];
        float cn = sigmoidf_(pf) * co + sigmoidf_(pi) * tanhf_(pg);
        cptr[idx] = cn;
        hout[idx] = f2bf(sigmoidf_(po) * tanhf_(cn));
      }
    }
  } else {
    // ---- projection role: out[b,t,:] = sigmoid(h2[t] @ W_out^T + b_out) ----
    const int t = k - 2;
    if (t < 0 || t > 127) return;
    const int bt = wg - 512;                  // 0..7 -> 64 batch rows each
    const unsigned short* hsrc = h2_ring + (size_t)(t & 1) * (B_ * H_);
    f32x4 acc[4];
#pragma unroll
    for (int j = 0; j < 4; ++j) acc[j] = (f32x4)0.0f;

    for (int kc = 0; kc < 16; ++kc) {
#pragma unroll
      for (int q2 = 0; q2 < 2; ++q2) {        // stage A: 64 rows x 128 B
        int q = w * 2 + q2;
        int rr = q * 8 + (l >> 3);
        int c  = l & 7;
        const unsigned short* srow = hsrc + (size_t)(bt * 64 + rr) * H_;
        gload16((const unsigned char*)srow + kc * 128 + ((c ^ (rr & 7)) * 16),
                ldsA + q * 1024);
      }
#pragma unroll
      for (int r2 = 0; r2 < 2; ++r2) {        // stage B: 8 frags (2 s2 x 4 j)
        int r  = w * 2 + r2;                  // r = s2*4 + j
        size_t frag = (size_t)(kc * 2 + (r >> 2)) * 4 + (r & 3);
        gload16((const unsigned char*)Woutp + frag * 1024 + (size_t)l * 16,
                ldsB + r * 1024);
      }
      __syncthreads();
#pragma unroll
      for (int s2 = 0; s2 < 2; ++s2) {
        int rl = w * 16 + (l & 15);
        int c  = s2 * 4 + (l >> 4);
        short8 a = *reinterpret_cast<const short8*>(ldsA + rl * 128 + ((c ^ (rl & 7)) * 16));
#pragma unroll
        for (int j = 0; j < 4; ++j) {
          short8 bb = *reinterpret_cast<const short8*>(ldsB + (s2 * 4 + j) * 1024 + l * 16);
          acc[j] = __builtin_amdgcn_mfma_f32_16x16x32_bf16(a, bb, acc[j], 0, 0, 0);
        }
      }
      __syncthreads();
    }
#pragma unroll
    for (int j = 0; j < 4; ++j) {
      int n = j * 16 + (l & 15);
      if (n < OUT_) {
#pragma unroll
        for (int r = 0; r < 4; ++r) {
          int b = bt * 64 + w * 16 + (l >> 4) * 4 + r;
          out[((size_t)b * S_ + t) * OUT_ + n] = sigmoidf_(acc[j][r] + b_out[n]);
        }
      }
    }
  }
}

// ---------------------------------------------------------------------------
extern "C" void kernel_launch(void* const* d_in, const int* in_sizes, int n_in,
                              void* d_out, int out_size, void* d_ws, size_t ws_size,
                              hipStream_t stream) {
  const float* z      = (const float*)d_in[0];
  const float* W_hid  = (const float*)d_in[1];
  const float* b_hid  = (const float*)d_in[2];
  const float* W_cell = (const float*)d_in[3];
  const float* b_cell = (const float*)d_in[4];
  // d_in[5] = W_ih0 : multiplied by zeros in the reference -> unused
  const float* W_hh0  = (const float*)d_in[6];
  const float* b_ih0  = (const float*)d_in[7];
  const float* b_hh0  = (const float*)d_in[8];
  const float* W_ih1  = (const float*)d_in[9];
  const float* W_hh1  = (const float*)d_in[10];
  const float* b_ih1  = (const float*)d_in[11];
  const float* b_hh1  = (const float*)d_in[12];
  const float* W_out  = (const float*)d_in[13];
  const float* b_out  = (const float*)d_in[14];
  float* out = (float*)d_out;

  // workspace layout (~32.2 MB)
  char* ws = (char*)d_ws;
  unsigned short* W0p   = (unsigned short*)(ws);                          // 8 MiB
  unsigned short* W1p   = (unsigned short*)(ws + (8u << 20));             // 16 MiB
  unsigned short* Woutp = (unsigned short*)(ws + (24u << 20));            // 128 KiB
  float* b0   = (float*)(ws + (24u << 20) + (1u << 17));
  float* b1   = b0 + 4096;
  float* c_l0 = (float*)(b1 + 4096);                                      // 2 MiB
  float* c_l1 = c_l0 + (size_t)B_ * H_;                                   // 2 MiB
  unsigned short* h1_ring = (unsigned short*)(c_l1 + (size_t)B_ * H_);    // 2 x 1 MiB
  unsigned short* h2_ring = h1_ring + 2 * (size_t)B_ * H_;                // 2 x 1 MiB

  // pack weights to fragment-linear bf16 (every call: no cross-call state)
  pack_frags_kernel<<<524288 / 256, 256, 0, stream>>>(W_hh0, W_hh0, W0p, 256, 32, 32, 4096, 1024);
  pack_frags_kernel<<<1048576 / 256, 256, 0, stream>>>(W_ih1, W_hh1, W1p, 256, 64, 32, 4096, 1024);
  pack_frags_kernel<<<8192 / 256, 256, 0, stream>>>(W_out, W_out, Woutp, 4, 32, 32, 49, 1024);
  prep_bias_kernel<<<16, 256, 0, stream>>>(b_ih0, b_hh0, b_ih1, b_hh1, b0, b1);
  init_hc_kernel<<<B_, 256, 0, stream>>>(z, W_hid, b_hid, W_cell, b_cell,
                                         h1_ring, h2_ring, c_l0, c_l1);
  // pipelined super-steps: L0(k) || L1(k-1) || proj(k-2)
  for (int k = 0; k < 130; ++k)
    step_kernel<<<520, 256, 0, stream>>>(k, W0p, W1p, Woutp, b0, b1, b_out,
                                         c_l0, c_l1, h1_ring, h2_ring, out);
}

// Round 2
// 3303.697 us; speedup vs baseline: 1.2664x; 1.2664x over previous
//
#include <hip/hip_runtime.h>
#include <stdint.h>

#define B_   512
#define H_   1024
#define S_   128
#define OUT_ 49

typedef __attribute__((ext_vector_type(8))) short short8;
typedef __attribute__((ext_vector_type(4))) float f32x4;

#define VMW(n)  asm volatile("s_waitcnt vmcnt(" #n ")" ::: "memory")
#define SBAR()  __builtin_amdgcn_s_barrier()
#define MEMF()  asm volatile("" ::: "memory")

__device__ __forceinline__ unsigned short f2bf(float f) {
  union { float f; uint32_t u; } v; v.f = f;
  return (unsigned short)((v.u + 0x7FFFu + ((v.u >> 16) & 1u)) >> 16);  // RNE
}
__device__ __forceinline__ float sigmoidf_(float x) { return 1.0f / (1.0f + __expf(-x)); }
__device__ __forceinline__ float tanhf_(float x)    { return 2.0f / (1.0f + __expf(-2.0f * x)) - 1.0f; }

__device__ __forceinline__ void gload16(const void* gp, void* lp) {
  __builtin_amdgcn_global_load_lds(
      (const __attribute__((address_space(1))) void*)gp,
      (__attribute__((address_space(3))) void*)lp, 16, 0, 0);
}

// ---------------------------------------------------------------------------
// Pack fp32 weights into MFMA-fragment-linear bf16 (unchanged from R1).
// ---------------------------------------------------------------------------
__global__ void pack_frags_kernel(const float* __restrict__ srcA,
                                  const float* __restrict__ srcB,
                                  unsigned short* __restrict__ dst,
                                  int RT, int S_total, int s_split,
                                  int src_rows, int src_cols) {
  int gid = blockIdx.x * blockDim.x + threadIdx.x;
  int total = S_total * RT * 64;
  if (gid >= total) return;
  int l  = gid & 63;
  int rt = (gid >> 6) % RT;
  int s  = gid / (RT * 64);
  int row = rt * 16 + (l & 15);
  const float* src = srcA;
  int scol = s;
  if (s >= s_split) { src = srcB; scol = s - s_split; }
  int col = scol * 32 + (l >> 4) * 8;
  short8 v;
  if (row < src_rows) {
    const float* p = src + (size_t)row * src_cols + col;
#pragma unroll
    for (int e = 0; e < 8; ++e) v[e] = (short)f2bf(p[e]);
  } else {
#pragma unroll
    for (int e = 0; e < 8; ++e) v[e] = 0;
  }
  *reinterpret_cast<short8*>(dst + (size_t)gid * 8) = v;
}

__global__ void prep_bias_kernel(const float* __restrict__ bi0, const float* __restrict__ bh0,
                                 const float* __restrict__ bi1, const float* __restrict__ bh1,
                                 float* __restrict__ b0, float* __restrict__ b1) {
  int i = blockIdx.x * blockDim.x + threadIdx.x;
  if (i < 4096) { b0[i] = bi0[i] + bh0[i]; b1[i] = bi1[i] + bh1[i]; }
}

// ---------------------------------------------------------------------------
// init h/c: [512,2048] = z @ W^T + b. Tiled: block = 64 batch x 32 j,
// z block staged in LDS, W rows read as float4 (shared by 8 lanes).
// ---------------------------------------------------------------------------
__global__ __launch_bounds__(256)
void init_hc_kernel(const float* __restrict__ z,
                    const float* __restrict__ W_hid, const float* __restrict__ b_hid,
                    const float* __restrict__ W_cell, const float* __restrict__ b_cell,
                    unsigned short* __restrict__ h1_ring, unsigned short* __restrict__ h2_ring,
                    float* __restrict__ c_l0, float* __restrict__ c_l1) {
  __shared__ float zs[64][64];
  const int bt = blockIdx.x & 7, jt = blockIdx.x >> 3;
  const int tid = threadIdx.x;
#pragma unroll
  for (int p = 0; p < 4; ++p) {
    int f = (tid + p * 256) * 4;          // [0,4096)
    int r = f >> 6, c = f & 63;
    *reinterpret_cast<f32x4*>(&zs[r][c]) =
        *reinterpret_cast<const f32x4*>(&z[(size_t)(bt * 64 + r) * 64 + c]);
  }
  __syncthreads();
  const int jj = tid & 31, bg = tid >> 5;
  const int j = jt * 32 + jj;
  float acch[8], accc[8];
  const float bh = b_hid[j], bc = b_cell[j];
#pragma unroll
  for (int i = 0; i < 8; ++i) { acch[i] = bh; accc[i] = bc; }
  const f32x4* wh4 = reinterpret_cast<const f32x4*>(W_hid + (size_t)j * 64);
  const f32x4* wc4 = reinterpret_cast<const f32x4*>(W_cell + (size_t)j * 64);
#pragma unroll 4
  for (int k4 = 0; k4 < 16; ++k4) {
    f32x4 wh = wh4[k4], wc = wc4[k4];
#pragma unroll
    for (int i = 0; i < 8; ++i) {
      f32x4 zz = *reinterpret_cast<const f32x4*>(&zs[bg * 8 + i][k4 * 4]);
      acch[i] += zz[0]*wh[0] + zz[1]*wh[1] + zz[2]*wh[2] + zz[3]*wh[3];
      accc[i] += zz[0]*wc[0] + zz[1]*wc[1] + zz[2]*wc[2] + zz[3]*wc[3];
    }
  }
  const int layer = j >> 10, n = j & 1023;
#pragma unroll
  for (int i = 0; i < 8; ++i) {
    int b = bt * 64 + bg * 8 + i;
    size_t idx = (size_t)b * H_ + n;
    if (layer == 0) { h1_ring[(size_t)B_ * H_ + idx] = f2bf(acch[i]); c_l0[idx] = accc[i]; }
    else            { h2_ring[(size_t)B_ * H_ + idx] = f2bf(acch[i]); c_l1[idx] = accc[i]; }
  }
}

// ---------------------------------------------------------------------------
// Super-step kernel, launch k = 0..129. Grid = 392 WGs:
//   [0,128)   : layer-0 step t=k,   BM=128 (bt in [0,4)), 32 MFMA/chunk/wave
//   [128,384) : layer-1 step t=k-1, BM=64  (bt in [0,8)), K=2048 concat
//   [384,392) : projection step t=k-2
// XCD-stable encoding: id%8 == nt2&7 in every segment (segment bases %8==0),
// so each XCD re-reads the same ~3 MiB weight slice every launch -> L2-hit.
// Double-buffered staging, counted vmcnt (never 0 mid-loop), raw s_barrier.
// LDS: A dbuf 2x16K at 0, B dbuf 2x16K at 32K (64 KiB dynamic).
// ---------------------------------------------------------------------------
__global__ __launch_bounds__(256)
void step_kernel(int k,
                 const unsigned short* __restrict__ W0p, const unsigned short* __restrict__ W1p,
                 const unsigned short* __restrict__ Woutp,
                 const float* __restrict__ b0, const float* __restrict__ b1,
                 const float* __restrict__ b_out,
                 float* __restrict__ c_l0, float* __restrict__ c_l1,
                 unsigned short* __restrict__ h1_ring, unsigned short* __restrict__ h2_ring,
                 float* __restrict__ out) {
  extern __shared__ __attribute__((aligned(128))) unsigned char smem[];
  unsigned char* bufA0 = smem;
  unsigned char* bufA1 = smem + 16384;
  unsigned char* bufB0 = smem + 32768;
  unsigned char* bufB1 = smem + 49152;
  const int wg  = blockIdx.x;
  const int tid = threadIdx.x;
  const int w = tid >> 6, l = tid & 63;
  const int wm = w >> 1, wn = w & 1;

  if (wg < 128) {
    // =================== layer 0, BM=128 ===================
    const int t = k;
    if (t > 127) return;
    const int x = wg & 7, bt = (wg >> 3) & 3, nt2 = (wg >> 5) * 8 + x;
    const unsigned short* hprev = h1_ring + (size_t)((t + 1) & 1) * (B_ * H_);
    unsigned short* hout        = h1_ring + (size_t)(t & 1) * (B_ * H_);

    f32x4 acc[4][4];
#pragma unroll
    for (int mt = 0; mt < 4; ++mt)
#pragma unroll
      for (int g = 0; g < 4; ++g) acc[mt][g] = (f32x4)0.0f;

    // stage(kc, bufs): A 128x128B (4 issues/wave) + B 16 frags (4 issues/wave)
#define STAGE_L0(KC_, A_, B_) do {                                             \
    int kc_ = (KC_);                                                           \
    _Pragma("unroll")                                                          \
    for (int q2 = 0; q2 < 4; ++q2) {                                           \
      int q = w * 4 + q2;                                                      \
      int rr = q * 8 + (l >> 3);                                               \
      int c  = l & 7;                                                          \
      gload16((const unsigned char*)(hprev + (size_t)(bt * 128 + rr) * H_)     \
                  + kc_ * 128 + ((c ^ (rr & 7)) * 16),                         \
              (A_) + q * 1024);                                                \
    }                                                                          \
    _Pragma("unroll")                                                          \
    for (int r2 = 0; r2 < 4; ++r2) {                                           \
      int r = w * 4 + r2;                                                      \
      int s2 = r >> 3, gg = (r >> 1) & 3, jjq = r & 1;                         \
      size_t frag = ((size_t)(kc_ * 2 + s2) * 256) + (size_t)gg * 64 + (nt2 * 2 + jjq); \
      gload16((const unsigned char*)W0p + frag * 1024 + (size_t)l * 16,        \
              (B_) + r * 1024);                                                \
    } } while (0)

    STAGE_L0(0, bufA0, bufB0);
    for (int kc = 0; kc < 16; ++kc) {
      unsigned char* curA = (kc & 1) ? bufA1 : bufA0;
      unsigned char* curB = (kc & 1) ? bufB1 : bufB0;
      if (kc + 1 < 16) {
        unsigned char* nxA = (kc & 1) ? bufA0 : bufA1;
        unsigned char* nxB = (kc & 1) ? bufB0 : bufB1;
        STAGE_L0(kc + 1, nxA, nxB);
        VMW(8);
      } else {
        VMW(0);
      }
      SBAR(); MEMF();
#pragma unroll
      for (int s2 = 0; s2 < 2; ++s2) {
        short8 a[4], bb[4];
#pragma unroll
        for (int mt = 0; mt < 4; ++mt) {
          int rl = wm * 64 + mt * 16 + (l & 15);
          int c  = s2 * 4 + (l >> 4);
          a[mt] = *reinterpret_cast<const short8*>(curA + rl * 128 + ((c ^ (rl & 7)) * 16));
        }
#pragma unroll
        for (int g = 0; g < 4; ++g)
          bb[g] = *reinterpret_cast<const short8*>(curB + (s2 * 8 + g * 2 + wn) * 1024 + l * 16);
#pragma unroll
        for (int mt = 0; mt < 4; ++mt)
#pragma unroll
          for (int g = 0; g < 4; ++g)
            acc[mt][g] = __builtin_amdgcn_mfma_f32_16x16x32_bf16(a[mt], bb[g], acc[mt][g], 0, 0, 0);
      }
      MEMF(); SBAR();
    }
    const int n = nt2 * 32 + wn * 16 + (l & 15);
#pragma unroll
    for (int mt = 0; mt < 4; ++mt) {
#pragma unroll
      for (int r = 0; r < 4; ++r) {
        int m = bt * 128 + wm * 64 + mt * 16 + (l >> 4) * 4 + r;
        float pi = acc[mt][0][r] + b0[n];
        float pf = acc[mt][1][r] + b0[1024 + n];
        float pg = acc[mt][2][r] + b0[2048 + n];
        float po = acc[mt][3][r] + b0[3072 + n];
        size_t idx = (size_t)m * H_ + n;
        float co = c_l0[idx];
        float cn = sigmoidf_(pf) * co + sigmoidf_(pi) * tanhf_(pg);
        c_l0[idx] = cn;
        hout[idx] = f2bf(sigmoidf_(po) * tanhf_(cn));
      }
    }
  } else if (wg < 384) {
    // =================== layer 1, BM=64, K=2048 concat [x|h] ===================
    const int t = k - 1;
    if (t < 0 || t > 127) return;
    const int id = wg - 128;
    const int x = id & 7, bt = (id >> 3) & 7, nt2 = (id >> 6) * 8 + x;
    const unsigned short* hprev = h2_ring + (size_t)((t + 1) & 1) * (B_ * H_);
    const unsigned short* xsrc  = h1_ring + (size_t)(t & 1) * (B_ * H_);
    unsigned short* hout        = h2_ring + (size_t)(t & 1) * (B_ * H_);

    f32x4 acc[2][4];
#pragma unroll
    for (int mt = 0; mt < 2; ++mt)
#pragma unroll
      for (int g = 0; g < 4; ++g) acc[mt][g] = (f32x4)0.0f;

#define STAGE_L1(KC_, A_, B_) do {                                             \
    int kc_ = (KC_);                                                           \
    const unsigned short* srcb = (kc_ < 16) ? xsrc : hprev;                    \
    int kbyte = (kc_ < 16) ? kc_ * 128 : (kc_ - 16) * 128;                     \
    _Pragma("unroll")                                                          \
    for (int q2 = 0; q2 < 2; ++q2) {                                           \
      int q = w * 2 + q2;                                                      \
      int rr = q * 8 + (l >> 3);                                               \
      int c  = l & 7;                                                          \
      gload16((const unsigned char*)(srcb + (size_t)(bt * 64 + rr) * H_)       \
                  + kbyte + ((c ^ (rr & 7)) * 16),                             \
              (A_) + q * 1024);                                                \
    }                                                                          \
    _Pragma("unroll")                                                          \
    for (int r2 = 0; r2 < 4; ++r2) {                                           \
      int r = w * 4 + r2;                                                      \
      int s2 = r >> 3, gg = (r >> 1) & 3, jjq = r & 1;                         \
      size_t frag = ((size_t)(kc_ * 2 + s2) * 256) + (size_t)gg * 64 + (nt2 * 2 + jjq); \
      gload16((const unsigned char*)W1p + frag * 1024 + (size_t)l * 16,        \
              (B_) + r * 1024);                                                \
    } } while (0)

    STAGE_L1(0, bufA0, bufB0);
    for (int kc = 0; kc < 32; ++kc) {
      unsigned char* curA = (kc & 1) ? bufA1 : bufA0;
      unsigned char* curB = (kc & 1) ? bufB1 : bufB0;
      if (kc + 1 < 32) {
        unsigned char* nxA = (kc & 1) ? bufA0 : bufA1;
        unsigned char* nxB = (kc & 1) ? bufB0 : bufB1;
        STAGE_L1(kc + 1, nxA, nxB);
        VMW(6);
      } else {
        VMW(0);
      }
      SBAR(); MEMF();
#pragma unroll
      for (int s2 = 0; s2 < 2; ++s2) {
        short8 a[2], bb[4];
#pragma unroll
        for (int mt = 0; mt < 2; ++mt) {
          int rl = wm * 32 + mt * 16 + (l & 15);
          int c  = s2 * 4 + (l >> 4);
          a[mt] = *reinterpret_cast<const short8*>(curA + rl * 128 + ((c ^ (rl & 7)) * 16));
        }
#pragma unroll
        for (int g = 0; g < 4; ++g)
          bb[g] = *reinterpret_cast<const short8*>(curB + (s2 * 8 + g * 2 + wn) * 1024 + l * 16);
#pragma unroll
        for (int mt = 0; mt < 2; ++mt)
#pragma unroll
          for (int g = 0; g < 4; ++g)
            acc[mt][g] = __builtin_amdgcn_mfma_f32_16x16x32_bf16(a[mt], bb[g], acc[mt][g], 0, 0, 0);
      }
      MEMF(); SBAR();
    }
    const int n = nt2 * 32 + wn * 16 + (l & 15);
#pragma unroll
    for (int mt = 0; mt < 2; ++mt) {
#pragma unroll
      for (int r = 0; r < 4; ++r) {
        int m = bt * 64 + wm * 32 + mt * 16 + (l >> 4) * 4 + r;
        float pi = acc[mt][0][r] + b1[n];
        float pf = acc[mt][1][r] + b1[1024 + n];
        float pg = acc[mt][2][r] + b1[2048 + n];
        float po = acc[mt][3][r] + b1[3072 + n];
        size_t idx = (size_t)m * H_ + n;
        float co = c_l1[idx];
        float cn = sigmoidf_(pf) * co + sigmoidf_(pi) * tanhf_(pg);
        c_l1[idx] = cn;
        hout[idx] = f2bf(sigmoidf_(po) * tanhf_(cn));
      }
    }
  } else {
    // =================== projection, BM=64 ===================
    const int t = k - 2;
    if (t < 0 || t > 127) return;
    const int bt = wg - 384;
    const unsigned short* hsrc = h2_ring + (size_t)(t & 1) * (B_ * H_);
    f32x4 acc[4];
#pragma unroll
    for (int j = 0; j < 4; ++j) acc[j] = (f32x4)0.0f;

#define STAGE_PJ(KC_, A_, B_) do {                                             \
    int kc_ = (KC_);                                                           \
    _Pragma("unroll")                                                          \
    for (int q2 = 0; q2 < 2; ++q2) {                                           \
      int q = w * 2 + q2;                                                      \
      int rr = q * 8 + (l >> 3);                                               \
      int c  = l & 7;                                                          \
      gload16((const unsigned char*)(hsrc + (size_t)(bt * 64 + rr) * H_)       \
                  + kc_ * 128 + ((c ^ (rr & 7)) * 16),                         \
              (A_) + q * 1024);                                                \
    }                                                                          \
    _Pragma("unroll")                                                          \
    for (int r2 = 0; r2 < 2; ++r2) {                                           \
      int r = w * 2 + r2;                                                      \
      size_t frag = (size_t)(kc_ * 2 + (r >> 2)) * 4 + (r & 3);                \
      gload16((const unsigned char*)Woutp + frag * 1024 + (size_t)l * 16,      \
              (B_) + r * 1024);                                                \
    } } while (0)

    STAGE_PJ(0, bufA0, bufB0);
    for (int kc = 0; kc < 16; ++kc) {
      unsigned char* curA = (kc & 1) ? bufA1 : bufA0;
      unsigned char* curB = (kc & 1) ? bufB1 : bufB0;
      if (kc + 1 < 16) {
        unsigned char* nxA = (kc & 1) ? bufA0 : bufA1;
        unsigned char* nxB = (kc & 1) ? bufB0 : bufB1;
        STAGE_PJ(kc + 1, nxA, nxB);
        VMW(4);
      } else {
        VMW(0);
      }
      SBAR(); MEMF();
#pragma unroll
      for (int s2 = 0; s2 < 2; ++s2) {
        int rl = w * 16 + (l & 15);
        int c  = s2 * 4 + (l >> 4);
        short8 a = *reinterpret_cast<const short8*>(curA + rl * 128 + ((c ^ (rl & 7)) * 16));
#pragma unroll
        for (int j = 0; j < 4; ++j) {
          short8 bb = *reinterpret_cast<const short8*>(curB + (s2 * 4 + j) * 1024 + l * 16);
          acc[j] = __builtin_amdgcn_mfma_f32_16x16x32_bf16(a, bb, acc[j], 0, 0, 0);
        }
      }
      MEMF(); SBAR();
    }
#pragma unroll
    for (int j = 0; j < 4; ++j) {
      int n = j * 16 + (l & 15);
      if (n < OUT_) {
#pragma unroll
        for (int r = 0; r < 4; ++r) {
          int b = bt * 64 + w * 16 + (l >> 4) * 4 + r;
          out[((size_t)b * S_ + t) * OUT_ + n] = sigmoidf_(acc[j][r] + b_out[n]);
        }
      }
    }
  }
}

// ---------------------------------------------------------------------------
extern "C" void kernel_launch(void* const* d_in, const int* in_sizes, int n_in,
                              void* d_out, int out_size, void* d_ws, size_t ws_size,
                              hipStream_t stream) {
  const float* z      = (const float*)d_in[0];
  const float* W_hid  = (const float*)d_in[1];
  const float* b_hid  = (const float*)d_in[2];
  const float* W_cell = (const float*)d_in[3];
  const float* b_cell = (const float*)d_in[4];
  // d_in[5] = W_ih0 : multiplied by zeros in the reference -> unused
  const float* W_hh0  = (const float*)d_in[6];
  const float* b_ih0  = (const float*)d_in[7];
  const float* b_hh0  = (const float*)d_in[8];
  const float* W_ih1  = (const float*)d_in[9];
  const float* W_hh1  = (const float*)d_in[10];
  const float* b_ih1  = (const float*)d_in[11];
  const float* b_hh1  = (const float*)d_in[12];
  const float* W_out  = (const float*)d_in[13];
  const float* b_out  = (const float*)d_in[14];
  float* out = (float*)d_out;

  char* ws = (char*)d_ws;
  unsigned short* W0p   = (unsigned short*)(ws);                          // 8 MiB
  unsigned short* W1p   = (unsigned short*)(ws + (8u << 20));             // 16 MiB
  unsigned short* Woutp = (unsigned short*)(ws + (24u << 20));            // 128 KiB
  float* b0   = (float*)(ws + (24u << 20) + (1u << 17));
  float* b1   = b0 + 4096;
  float* c_l0 = (float*)(b1 + 4096);                                      // 2 MiB
  float* c_l1 = c_l0 + (size_t)B_ * H_;                                   // 2 MiB
  unsigned short* h1_ring = (unsigned short*)(c_l1 + (size_t)B_ * H_);    // 2 x 1 MiB
  unsigned short* h2_ring = h1_ring + 2 * (size_t)B_ * H_;                // 2 x 1 MiB

  pack_frags_kernel<<<524288 / 256, 256, 0, stream>>>(W_hh0, W_hh0, W0p, 256, 32, 32, 4096, 1024);
  pack_frags_kernel<<<1048576 / 256, 256, 0, stream>>>(W_ih1, W_hh1, W1p, 256, 64, 32, 4096, 1024);
  pack_frags_kernel<<<8192 / 256, 256, 0, stream>>>(W_out, W_out, Woutp, 4, 32, 32, 49, 1024);
  prep_bias_kernel<<<16, 256, 0, stream>>>(b_ih0, b_hh0, b_ih1, b_hh1, b0, b1);
  init_hc_kernel<<<512, 256, 0, stream>>>(z, W_hid, b_hid, W_cell, b_cell,
                                          h1_ring, h2_ring, c_l0, c_l1);
  for (int k = 0; k < 130; ++k)
    step_kernel<<<392, 256, 65536, stream>>>(k, W0p, W1p, Woutp, b0, b1, b_out,
                                             c_l0, c_l1, h1_ring, h2_ring, out);
}